// Round 22
// baseline (124.479 us; speedup 1.0000x reference)
//
#include <hip/hip_runtime.h>

#define WDIM  256
#define NSAMP 512
#define NSIG  32
#define NBLK  2048               // 512 samples x 4 quarters
#define QOFF  16                 // ints; queue table q[QOFF..]
#define WOFF  65536              // byte offset of W matrices inside d_ws
#define TOFF  (WOFF + NSIG * WDIM * WDIM * 2)   // byte offset of Yh^T tmp

typedef float    f32x4 __attribute__((ext_vector_type(4)));
typedef _Float16 f16x4 __attribute__((ext_vector_type(4)));
typedef _Float16 f16x8 __attribute__((ext_vector_type(8)));
typedef __fp16   fp16x2 __attribute__((ext_vector_type(2)));

// Raw barrier without the __syncthreads vmcnt(0) drain (T4 minimal form).
#define LDS_BARRIER() do {                                         \
    asm volatile("s_waitcnt lgkmcnt(0)" ::: "memory");             \
    __builtin_amdgcn_s_barrier();                                  \
} while (0)

__device__ __forceinline__ int reflect(int q) {
    q = (q < 0) ? (-q - 1) : q;
    return (q >= WDIM) ? (2 * WDIM - 1 - q) : q;
}

// ---- kernel 1 (merged): blocks 0..255 build W matrices; block 256 the queue.
// W_s[i][r] = wz(r-i)+wz(-r-1-i)+wz(511-r-i); desc = samp|quarter<<9|step<<11|rad<<16.
__global__ __launch_bounds__(256) void build_all(const float* __restrict__ sigmas,
                                                 const int* __restrict__ steps,
                                                 _Float16* __restrict__ Wg,
                                                 int* __restrict__ q) {
    int t = threadIdx.x;
    if (blockIdx.x < 256) {
        __shared__ float wl[161];
        __shared__ float red;
        int s = blockIdx.x >> 3, og = blockIdx.x & 7;
        float sigma = sigmas[s];
        float radf = floorf(4.0f * sigma + 0.5f);
        if (t < 161) {
            float off = (float)(t - 80);
            float w = 0.0f;
            if (fabsf(off) <= radf) { float z = off / sigma; w = expf(-0.5f * z * z); }
            wl[t] = w;
        }
        __syncthreads();
        if (t < 64) {
            float v = wl[t] + wl[t + 64] + (t < 33 ? wl[t + 128] : 0.0f);
            #pragma unroll
            for (int o = 32; o > 0; o >>= 1) v += __shfl_down(v, o);
            if (t == 0) red = 1.0f / v;
        }
        __syncthreads();
        float rs = red;
        int i = t;
        _Float16* wrow = Wg + ((size_t)s << 16) + (i << 8);
        for (int rq = og * 4; rq < og * 4 + 4; ++rq) {
            f16x8 v;
            #pragma unroll
            for (int j = 0; j < 8; ++j) {
                int r = rq * 8 + j;
                int d1 = r - i, d2 = -r - 1 - i, d3 = 511 - r - i;
                float w = 0.0f;
                if (d1 >= -80 && d1 <= 80) w += wl[d1 + 80];
                if (d2 >= -80)             w += wl[d2 + 80];
                if (d3 <= 80)              w += wl[d3 + 80];
                v[j] = (_Float16)(w * rs);
            }
            *(f16x8*)(wrow + rq * 8) = v;
        }
    } else {
        __shared__ int hist[32];
        __shared__ int base[32];
        if (t < 32) hist[t] = 0;
        __syncthreads();
        int nb2[2], rd2[2], st2[2];
        #pragma unroll
        for (int k = 0; k < 2; ++k) {
            int samp = t + 256 * k;
            int st = steps[samp];
            float sigma = sigmas[st];
            int rad = (int)floorf(4.0f * sigma + 0.5f);
            st2[k] = st; rd2[k] = rad;
            nb2[k] = (2 * rad + 15) >> 3;
            atomicAdd(&hist[nb2[k]], 1);
        }
        __syncthreads();
        if (t == 0) {
            int acc = 0;
            for (int bin = 31; bin >= 0; --bin) { base[bin] = acc; acc += hist[bin]; }
        }
        __syncthreads();
        #pragma unroll
        for (int k = 0; k < 2; ++k) {
            int samp = t + 256 * k;
            int r = atomicAdd(&base[nb2[k]], 1);
            int x = r & 7;
            int p = r >> 3;
            #pragma unroll
            for (int jb = 0; jb < 4; ++jb)
                q[QOFF + (((p << 2) + jb) << 3) + x] =
                    samp | (jb << 9) | (st2[k] << 11) | (rd2[k] << 16);
        }
    }
}

// ---- kernel H: Yh[r][j] = sum_c X[r][c] W[j][c]; block = sample x 64-j quarter.
// A=X staged LDS (f32->f16 swizzled), B=W staged LDS; writes Yh^T (f16) to tmp.
template <bool QUEUED>
__global__ __launch_bounds__(256, 4) void blur_h(const float* __restrict__ in,
                                                 _Float16* __restrict__ tmp,
                                                 const float* __restrict__ sigmas,
                                                 const int* __restrict__ steps,
                                                 const int* __restrict__ q,
                                                 const _Float16* __restrict__ Wg) {
    __shared__ alignas(16) _Float16 XL[256 * 32];   // 16 KB
    __shared__ alignas(16) _Float16 WH[64 * 32];    //  4 KB

    int b, j0, s, rad;
    if constexpr (QUEUED) {
        int d = q[QOFF + blockIdx.x];
        b = d & 511; j0 = ((d >> 9) & 3) << 6; s = (d >> 11) & 31; rad = (d >> 16) & 127;
    } else {
        int bid = blockIdx.x;
        int e = (bid & 7) * (NBLK / 8) + (bid >> 3);
        b = e >> 2; j0 = (e & 3) << 6;
        s = steps[b];
        rad = (int)floorf(4.0f * sigmas[s] + 0.5f);
    }
    const _Float16* Wm = Wg + ((size_t)s << 16);
    const float*    Xb = in + ((size_t)b << 16);

    int tt = threadIdx.x;
    int ln = tt & 63, wv = tt >> 6;
    int lm = ln & 15, lq = ln >> 4;
    int sr = tt >> 3;             // X stage row base (0..31)
    int sc = (tt & 7) * 4;        // X stage col
    int sj = tt >> 2;             // W stage j (0..63)
    int sw8 = (tt & 3) * 8;       // W stage c chunk

    int kh0 = max(0, j0 - rad) >> 5;
    int kh1 = min(WDIM - 1, j0 + 63 + rad) >> 5;

    f32x4 xs[8];
    f16x8 wst;
    auto ldstage = [&](int kt) {
        const float* xp = Xb + (size_t)sr * WDIM + (kt << 5) + sc;
        #pragma unroll
        for (int k = 0; k < 8; ++k)
            xs[k] = *(const f32x4*)(xp + (size_t)(k * 32) * WDIM);
        wst = *(const f16x8*)(Wm + (size_t)(j0 + sj) * WDIM + (kt << 5) + sw8);
    };
    auto wrstage = [&]() {
        #pragma unroll
        for (int k = 0; k < 8; ++k) {
            int rr = sr + 32 * k;
            union { f16x4 v; fp16x2 h[2]; } u;
            u.h[0] = __builtin_amdgcn_cvt_pkrtz(xs[k][0], xs[k][1]);
            u.h[1] = __builtin_amdgcn_cvt_pkrtz(xs[k][2], xs[k][3]);
            *(f16x4*)&XL[rr * 32 + ((((sc >> 3) ^ (rr & 3)) << 3) + (sc & 7))] = u.v;
        }
        *(f16x8*)&WH[sj * 32 + (((tt & 3) ^ (sj & 3)) << 3)] = wst;
    };

    f32x4 acc[4][4];
    #pragma unroll
    for (int mt = 0; mt < 4; ++mt)
        #pragma unroll
        for (int nt = 0; nt < 4; ++nt) acc[mt][nt] = (f32x4)0.0f;

    ldstage(kh0);
    for (int kt = kh0; kt <= kh1; ++kt) {
        wrstage();
        LDS_BARRIER();
        if (kt < kh1) ldstage(kt + 1);       // stays in flight across barriers
        f16x8 bf[4];
        #pragma unroll
        for (int nt = 0; nt < 4; ++nt) {
            int j = nt * 16 + lm;
            bf[nt] = *(const f16x8*)&WH[j * 32 + ((lq ^ (j & 3)) << 3)];
        }
        #pragma unroll
        for (int mt = 0; mt < 4; ++mt) {
            int r = wv * 64 + mt * 16 + lm;
            f16x8 af = *(const f16x8*)&XL[r * 32 + ((lq ^ (r & 3)) << 3)];
            #pragma unroll
            for (int nt = 0; nt < 4; ++nt)
                acc[mt][nt] = __builtin_amdgcn_mfma_f32_16x16x32_f16(af, bf[nt], acc[mt][nt], 0, 0, 0);
        }
        LDS_BARRIER();
    }

    // store Yh^T (f16): tmp[b][j][r], D row=(lq*4+g)->r, col=lm->j
    _Float16* tb = tmp + ((size_t)b << 16);
    #pragma unroll
    for (int mt = 0; mt < 4; ++mt)
        #pragma unroll
        for (int nt = 0; nt < 4; ++nt) {
            int r4 = wv * 64 + mt * 16 + lq * 4;
            int j  = j0 + nt * 16 + lm;
            union { f16x4 v; fp16x2 h[2]; } u;
            u.h[0] = __builtin_amdgcn_cvt_pkrtz(acc[mt][nt][0], acc[mt][nt][1]);
            u.h[1] = __builtin_amdgcn_cvt_pkrtz(acc[mt][nt][2], acc[mt][nt][3]);
            *(f16x4*)&tb[(j << 8) + r4] = u.v;
        }
}

// ---- kernel V: Z[i][j] = sum_r W[i][r] Yh^T[j][r]; block = sample x 64-i quarter.
// NO LDS, NO barriers: A=W rows direct f16x8, B=tmp rows direct f16x8.
template <bool QUEUED>
__global__ __launch_bounds__(256, 4) void blur_v(const _Float16* __restrict__ tmp,
                                                 float* __restrict__ out,
                                                 const float* __restrict__ sigmas,
                                                 const int* __restrict__ steps,
                                                 const int* __restrict__ q,
                                                 const _Float16* __restrict__ Wg) {
    int b, i0, s, rad;
    if constexpr (QUEUED) {
        int d = q[QOFF + blockIdx.x];
        b = d & 511; i0 = ((d >> 9) & 3) << 6; s = (d >> 11) & 31; rad = (d >> 16) & 127;
    } else {
        int bid = blockIdx.x;
        int e = (bid & 7) * (NBLK / 8) + (bid >> 3);
        b = e >> 2; i0 = (e & 3) << 6;
        s = steps[b];
        rad = (int)floorf(4.0f * sigmas[s] + 0.5f);
    }
    const _Float16* Wm = Wg + ((size_t)s << 16);
    const _Float16* tb = tmp + ((size_t)b << 16);

    int ln = threadIdx.x & 63, wv = threadIdx.x >> 6;
    int lm = ln & 15, lq = ln >> 4;
    int jlo = wv * 64;

    f32x4 hac[4][4];
    #pragma unroll
    for (int mt = 0; mt < 4; ++mt)
        #pragma unroll
        for (int nt = 0; nt < 4; ++nt) hac[mt][nt] = (f32x4)0.0f;

    int ka[4], kb[4];
    #pragma unroll
    for (int mt = 0; mt < 4; ++mt) {
        int im = i0 + mt * 16;
        ka[mt] = max(0, im - rad) >> 5;
        kb[mt] = min(WDIM - 1, im + 15 + rad) >> 5;
    }

    for (int kt = ka[0]; kt <= kb[3]; ++kt) {
        f16x8 bf[4];
        #pragma unroll
        for (int nt = 0; nt < 4; ++nt) {
            int j = jlo + nt * 16 + lm;
            bf[nt] = *(const f16x8*)&tb[(j << 8) + (kt << 5) + lq * 8];
        }
        #pragma unroll
        for (int mt = 0; mt < 4; ++mt) {
            if (kt >= ka[mt] && kt <= kb[mt]) {
                f16x8 af = *(const f16x8*)(Wm + (size_t)(i0 + mt * 16 + lm) * WDIM + (kt << 5) + lq * 8);
                #pragma unroll
                for (int nt = 0; nt < 4; ++nt)
                    hac[mt][nt] = __builtin_amdgcn_mfma_f32_16x16x32_f16(af, bf[nt], hac[mt][nt], 0, 0, 0);
            }
        }
    }

    float* ob = out + ((size_t)b << 16);
    #pragma unroll
    for (int mt = 0; mt < 4; ++mt)
        #pragma unroll
        for (int nt = 0; nt < 4; ++nt)
            #pragma unroll
            for (int g = 0; g < 4; ++g)
                ob[(size_t)(i0 + mt * 16 + lq * 4 + g) * WDIM + jlo + nt * 16 + lm] = hac[mt][nt][g];
}

// ---------- fallback path (only if ws too small; needs no workspace) ----------
__device__ __forceinline__ int make_weights161(int b, const float* __restrict__ sigmas,
                                               const int* __restrict__ steps,
                                               float* wl, float* red) {
    int t = threadIdx.x;
    float sigma = sigmas[steps[b]];
    float radf = floorf(4.0f * sigma + 0.5f);
    if (t < 192) {
        float w = 0.0f;
        if (t < 161) {
            float off = (float)(t - 80);
            if (fabsf(off) <= radf) { float z = off / sigma; w = expf(-0.5f * z * z); }
        }
        wl[t] = w;
    }
    __syncthreads();
    if (t < 64) {
        float v = wl[t] + wl[t + 64] + wl[t + 128];
        #pragma unroll
        for (int o = 32; o > 0; o >>= 1) v += __shfl_down(v, o);
        if (t == 0) red[0] = 1.0f / v;
    }
    __syncthreads();
    float rs = red[0];
    if (t < 161) wl[t] *= rs;
    __syncthreads();
    return (int)radf;
}

__global__ __launch_bounds__(256) void vblur_nt(const float* __restrict__ in,
                                                float* __restrict__ out,
                                                const float* __restrict__ sigmas,
                                                const int* __restrict__ steps) {
    __shared__ float wl[192];
    __shared__ float red[1];
    int bid = blockIdx.x;
    int b = bid >> 4, i0 = (bid & 15) * 16;
    int rad = make_weights161(b, sigmas, steps, wl, red);
    int j = threadIdx.x;
    const float* inb = in + (size_t)b * WDIM * WDIM;
    float acc[16];
    #pragma unroll
    for (int ii = 0; ii < 16; ++ii) acc[ii] = 0.0f;
    for (int u = -rad; u <= rad; ++u) {
        float w = wl[80 + u];
        #pragma unroll
        for (int ii = 0; ii < 16; ++ii)
            acc[ii] = fmaf(w, inb[reflect(i0 + ii + u) * WDIM + j], acc[ii]);
    }
    #pragma unroll
    for (int ii = 0; ii < 16; ++ii)
        out[((size_t)b * WDIM + (i0 + ii)) * WDIM + j] = acc[ii];
}

__global__ __launch_bounds__(256) void hblur_inplace(float* __restrict__ buf,
                                                     const float* __restrict__ sigmas,
                                                     const int* __restrict__ steps) {
    __shared__ float wl[192];
    __shared__ float red[1];
    __shared__ float rp[WDIM + 160];
    int bid = blockIdx.x;
    int b = bid >> 8, i = bid & 255;
    float* row = buf + ((size_t)b * WDIM + i) * WDIM;
    int t = threadIdx.x;
    for (int s = t; s < WDIM + 160; s += 256) rp[s] = row[reflect(s - 80)];
    int rad = make_weights161(b, sigmas, steps, wl, red);
    float acc = 0.0f;
    for (int u = -rad; u <= rad; ++u) acc = fmaf(wl[80 + u], rp[80 + t + u], acc);
    row[t] = acc;
}
// --------------------------------------------------------------------------------

extern "C" void kernel_launch(void* const* d_in, const int* in_sizes, int n_in,
                              void* d_out, int out_size, void* d_ws, size_t ws_size,
                              hipStream_t stream) {
    const float* x     = (const float*)d_in[0];
    const float* sig   = (const float*)d_in[1];
    const int*   steps = (const int*)d_in[2];
    float* out = (float*)d_out;

    const size_t need = (size_t)TOFF + (size_t)NSAMP * WDIM * WDIM * 2;
    if (ws_size >= need) {
        int* q = (int*)d_ws;
        _Float16* Wg  = (_Float16*)((char*)d_ws + WOFF);
        _Float16* tmp = (_Float16*)((char*)d_ws + TOFF);
        build_all<<<257, 256, 0, stream>>>(sig, steps, Wg, q);
        blur_h<true><<<NBLK, 256, 0, stream>>>(x, tmp, sig, steps, q, Wg);
        blur_v<true><<<NBLK, 256, 0, stream>>>(tmp, out, sig, steps, q, Wg);
    } else {
        vblur_nt<<<NSAMP * 16, 256, 0, stream>>>(x, out, sig, steps);
        hblur_inplace<<<NSAMP * WDIM, 256, 0, stream>>>(out, sig, steps);
    }
}

// Round 23
// 90.291 us; speedup vs baseline: 1.3786x; 1.3786x over previous
//
#include <hip/hip_runtime.h>

#define WDIM  256
#define NSAMP 512
#define NSIG  32
#define NBLK  2048               // 512 samples x 4 j-quarters
#define QOFF  16                 // ints; queue table q[QOFF..]
#define WOFF  65536              // byte offset of W matrices inside d_ws

typedef float    f32x4 __attribute__((ext_vector_type(4)));
typedef _Float16 f16x4 __attribute__((ext_vector_type(4)));
typedef _Float16 f16x8 __attribute__((ext_vector_type(8)));
typedef __fp16   fp16x2 __attribute__((ext_vector_type(2)));

// Raw barrier without the __syncthreads vmcnt(0) drain.
#define LDS_BARRIER() do {                                         \
    asm volatile("s_waitcnt lgkmcnt(0)" ::: "memory");             \
    __builtin_amdgcn_s_barrier();                                  \
} while (0)

__device__ __forceinline__ int reflect(int q) {
    q = (q < 0) ? (-q - 1) : q;
    return (q >= WDIM) ? (2 * WDIM - 1 - q) : q;
}

// ---- kernel 1 (merged): blocks 0..255 build W matrices; block 256 the queue.
// W_s[i][r] = wz(r-i)+wz(-r-1-i)+wz(511-r-i); desc = samp|quarter<<9|step<<11|rad<<16.
__global__ __launch_bounds__(256) void build_all(const float* __restrict__ sigmas,
                                                 const int* __restrict__ steps,
                                                 _Float16* __restrict__ Wg,
                                                 int* __restrict__ q) {
    int t = threadIdx.x;
    if (blockIdx.x < 256) {
        __shared__ float wl[161];
        __shared__ float red;
        int s = blockIdx.x >> 3, og = blockIdx.x & 7;
        float sigma = sigmas[s];
        float radf = floorf(4.0f * sigma + 0.5f);
        if (t < 161) {
            float off = (float)(t - 80);
            float w = 0.0f;
            if (fabsf(off) <= radf) { float z = off / sigma; w = expf(-0.5f * z * z); }
            wl[t] = w;
        }
        __syncthreads();
        if (t < 64) {
            float v = wl[t] + wl[t + 64] + (t < 33 ? wl[t + 128] : 0.0f);
            #pragma unroll
            for (int o = 32; o > 0; o >>= 1) v += __shfl_down(v, o);
            if (t == 0) red = 1.0f / v;
        }
        __syncthreads();
        float rs = red;
        int i = t;
        _Float16* wrow = Wg + ((size_t)s << 16) + (i << 8);
        for (int rq = og * 4; rq < og * 4 + 4; ++rq) {
            f16x8 v;
            #pragma unroll
            for (int j = 0; j < 8; ++j) {
                int r = rq * 8 + j;
                int d1 = r - i, d2 = -r - 1 - i, d3 = 511 - r - i;
                float w = 0.0f;
                if (d1 >= -80 && d1 <= 80) w += wl[d1 + 80];
                if (d2 >= -80)             w += wl[d2 + 80];
                if (d3 <= 80)              w += wl[d3 + 80];
                v[j] = (_Float16)(w * rs);
            }
            *(f16x8*)(wrow + rq * 8) = v;
        }
    } else {
        __shared__ int hist[32];
        __shared__ int base[32];
        if (t < 32) hist[t] = 0;
        __syncthreads();
        int nb2[2], rd2[2], st2[2];
        #pragma unroll
        for (int k = 0; k < 2; ++k) {
            int samp = t + 256 * k;
            int st = steps[samp];
            float sigma = sigmas[st];
            int rad = (int)floorf(4.0f * sigma + 0.5f);
            st2[k] = st; rd2[k] = rad;
            nb2[k] = (2 * rad + 15) >> 3;
            atomicAdd(&hist[nb2[k]], 1);
        }
        __syncthreads();
        if (t == 0) {
            int acc = 0;
            for (int bin = 31; bin >= 0; --bin) { base[bin] = acc; acc += hist[bin]; }
        }
        __syncthreads();
        #pragma unroll
        for (int k = 0; k < 2; ++k) {
            int samp = t + 256 * k;
            int r = atomicAdd(&base[nb2[k]], 1);
            int x = r & 7;
            int p = r >> 3;
            #pragma unroll
            for (int jb = 0; jb < 4; ++jb)
                q[QOFF + (((p << 2) + jb) << 3) + x] =
                    samp | (jb << 9) | (st2[k] << 11) | (rd2[k] << 16);
        }
    }
}

// ---- kernel 2: fused MFMA blur, BOTH phases direct-load (V-style). ----
// Phase H (barrier-free): Yh[r][j] = sum_c X[r][c] W[j][c].
//   A-frag = X[r][c-chunk] direct f32 (2x f32x4 + pkrtz), B-frag = W[j][c-chunk]
//   direct f16x8. All row-contiguous. Yh^T -> swizzled LDS YT.
// ONE barrier. Phase V (barrier-free): Z[i][j] = sum_r W[i][r] Yh^T[j][r];
//   A-frag = W rows direct f16x8, B-frag = YT LDS (2-way conflict = free).
template <bool QUEUED>
__global__ __launch_bounds__(256, 3) void blur_mfma(const float* __restrict__ in,
                                                    float* __restrict__ out,
                                                    const float* __restrict__ sigmas,
                                                    const int* __restrict__ steps,
                                                    const int* __restrict__ q,
                                                    const _Float16* __restrict__ Wg) {
    __shared__ alignas(16) _Float16 YT[64 * 256];   // 32 KB: Yh^T, swizzled

    int b, j0, s, rad;
    if constexpr (QUEUED) {
        int d = q[QOFF + blockIdx.x];
        b = d & 511; j0 = ((d >> 9) & 3) << 6; s = (d >> 11) & 31; rad = (d >> 16) & 127;
    } else {
        int bid = blockIdx.x;
        int e = (bid & 7) * (NBLK / 8) + (bid >> 3);
        b = e >> 2; j0 = (e & 3) << 6;
        s = steps[b];
        rad = (int)floorf(4.0f * sigmas[s] + 0.5f);
    }
    const _Float16* Wm = Wg + ((size_t)s << 16);
    const float*    Xb = in + ((size_t)b << 16);

    int ln = threadIdx.x & 63, wv = threadIdx.x >> 6;
    int lm = ln & 15, lq = ln >> 4;

    // ---------------- Phase H (no LDS inputs, no barriers) ----------------
    f32x4 acc[4][4];
    #pragma unroll
    for (int mt = 0; mt < 4; ++mt)
        #pragma unroll
        for (int nt = 0; nt < 4; ++nt) acc[mt][nt] = (f32x4)0.0f;

    int kh0 = max(0, j0 - rad) >> 5;
    int kh1 = min(WDIM - 1, j0 + 63 + rad) >> 5;

    for (int kt = kh0; kt <= kh1; ++kt) {
        // issue ALL tile loads first (bf f16x8 + per-mt X f32x4 pairs)
        f16x8 bf[4];
        #pragma unroll
        for (int nt = 0; nt < 4; ++nt)
            bf[nt] = *(const f16x8*)(Wm + (size_t)(j0 + nt * 16 + lm) * WDIM + (kt << 5) + lq * 8);
        f32x4 xlo[4], xhi[4];
        #pragma unroll
        for (int mt = 0; mt < 4; ++mt) {
            const float* xp = Xb + (size_t)(wv * 64 + mt * 16 + lm) * WDIM + (kt << 5) + lq * 8;
            xlo[mt] = *(const f32x4*)xp;
            xhi[mt] = *(const f32x4*)(xp + 4);
        }
        // convert + MFMA
        #pragma unroll
        for (int mt = 0; mt < 4; ++mt) {
            union { f16x8 v; fp16x2 h[4]; } u;
            u.h[0] = __builtin_amdgcn_cvt_pkrtz(xlo[mt][0], xlo[mt][1]);
            u.h[1] = __builtin_amdgcn_cvt_pkrtz(xlo[mt][2], xlo[mt][3]);
            u.h[2] = __builtin_amdgcn_cvt_pkrtz(xhi[mt][0], xhi[mt][1]);
            u.h[3] = __builtin_amdgcn_cvt_pkrtz(xhi[mt][2], xhi[mt][3]);
            #pragma unroll
            for (int nt = 0; nt < 4; ++nt)
                acc[mt][nt] = __builtin_amdgcn_mfma_f32_16x16x32_f16(u.v, bf[nt], acc[mt][nt], 0, 0, 0);
        }
    }

    // Yh^T -> YT (swizzled, r21-validated addressing): D row=(lq*4+g)->r, col=lm->j
    #pragma unroll
    for (int mt = 0; mt < 4; ++mt)
        #pragma unroll
        for (int nt = 0; nt < 4; ++nt) {
            int r4 = wv * 64 + mt * 16 + lq * 4;
            int j  = nt * 16 + lm;
            union { f16x4 v; fp16x2 h[2]; } u;
            u.h[0] = __builtin_amdgcn_cvt_pkrtz(acc[mt][nt][0], acc[mt][nt][1]);
            u.h[1] = __builtin_amdgcn_cvt_pkrtz(acc[mt][nt][2], acc[mt][nt][3]);
            *(f16x4*)&YT[j * 256 + ((((r4 >> 3) ^ (j & 7)) << 3) + (r4 & 7))] = u.v;
        }
    LDS_BARRIER();   // the ONLY barrier in the kernel

    // ---------------- Phase V (no barriers) ----------------
    f32x4 hac[4][4];
    #pragma unroll
    for (int mt = 0; mt < 4; ++mt)
        #pragma unroll
        for (int nt = 0; nt < 4; ++nt) hac[mt][nt] = (f32x4)0.0f;

    int ka[4], kb[4];
    #pragma unroll
    for (int mt = 0; mt < 4; ++mt) {
        int i0m = wv * 64 + mt * 16;
        ka[mt] = max(0, i0m - rad) >> 5;
        kb[mt] = min(WDIM - 1, i0m + 15 + rad) >> 5;
    }

    for (int kt = ka[0]; kt <= kb[3]; ++kt) {
        f16x8 bf[4];
        #pragma unroll
        for (int nt = 0; nt < 4; ++nt) {
            int j = nt * 16 + lm;
            bf[nt] = *(const f16x8*)&YT[j * 256 + ((((kt << 2) + lq) ^ (j & 7)) << 3)];
        }
        #pragma unroll
        for (int mt = 0; mt < 4; ++mt) {
            if (kt >= ka[mt] && kt <= kb[mt]) {
                f16x8 af = *(const f16x8*)(Wm + (size_t)(wv * 64 + mt * 16 + lm) * WDIM + (kt << 5) + lq * 8);
                #pragma unroll
                for (int nt = 0; nt < 4; ++nt)
                    hac[mt][nt] = __builtin_amdgcn_mfma_f32_16x16x32_f16(af, bf[nt], hac[mt][nt], 0, 0, 0);
            }
        }
    }

    float* ob = out + ((size_t)b << 16);
    #pragma unroll
    for (int mt = 0; mt < 4; ++mt)
        #pragma unroll
        for (int nt = 0; nt < 4; ++nt)
            #pragma unroll
            for (int g = 0; g < 4; ++g)
                ob[(size_t)(wv * 64 + mt * 16 + lq * 4 + g) * WDIM + j0 + nt * 16 + lm] = hac[mt][nt][g];
}

// ---------- fallback path (only if ws too small; needs no workspace) ----------
__device__ __forceinline__ int make_weights161(int b, const float* __restrict__ sigmas,
                                               const int* __restrict__ steps,
                                               float* wl, float* red) {
    int t = threadIdx.x;
    float sigma = sigmas[steps[b]];
    float radf = floorf(4.0f * sigma + 0.5f);
    if (t < 192) {
        float w = 0.0f;
        if (t < 161) {
            float off = (float)(t - 80);
            if (fabsf(off) <= radf) { float z = off / sigma; w = expf(-0.5f * z * z); }
        }
        wl[t] = w;
    }
    __syncthreads();
    if (t < 64) {
        float v = wl[t] + wl[t + 64] + wl[t + 128];
        #pragma unroll
        for (int o = 32; o > 0; o >>= 1) v += __shfl_down(v, o);
        if (t == 0) red[0] = 1.0f / v;
    }
    __syncthreads();
    float rs = red[0];
    if (t < 161) wl[t] *= rs;
    __syncthreads();
    return (int)radf;
}

__global__ __launch_bounds__(256) void vblur_nt(const float* __restrict__ in,
                                                float* __restrict__ out,
                                                const float* __restrict__ sigmas,
                                                const int* __restrict__ steps) {
    __shared__ float wl[192];
    __shared__ float red[1];
    int bid = blockIdx.x;
    int b = bid >> 4, i0 = (bid & 15) * 16;
    int rad = make_weights161(b, sigmas, steps, wl, red);
    int j = threadIdx.x;
    const float* inb = in + (size_t)b * WDIM * WDIM;
    float acc[16];
    #pragma unroll
    for (int ii = 0; ii < 16; ++ii) acc[ii] = 0.0f;
    for (int u = -rad; u <= rad; ++u) {
        float w = wl[80 + u];
        #pragma unroll
        for (int ii = 0; ii < 16; ++ii)
            acc[ii] = fmaf(w, inb[reflect(i0 + ii + u) * WDIM + j], acc[ii]);
    }
    #pragma unroll
    for (int ii = 0; ii < 16; ++ii)
        out[((size_t)b * WDIM + (i0 + ii)) * WDIM + j] = acc[ii];
}

__global__ __launch_bounds__(256) void hblur_inplace(float* __restrict__ buf,
                                                     const float* __restrict__ sigmas,
                                                     const int* __restrict__ steps) {
    __shared__ float wl[192];
    __shared__ float red[1];
    __shared__ float rp[WDIM + 160];
    int bid = blockIdx.x;
    int b = bid >> 8, i = bid & 255;
    float* row = buf + ((size_t)b * WDIM + i) * WDIM;
    int t = threadIdx.x;
    for (int s = t; s < WDIM + 160; s += 256) rp[s] = row[reflect(s - 80)];
    int rad = make_weights161(b, sigmas, steps, wl, red);
    float acc = 0.0f;
    for (int u = -rad; u <= rad; ++u) acc = fmaf(wl[80 + u], rp[80 + t + u], acc);
    row[t] = acc;
}
// --------------------------------------------------------------------------------

extern "C" void kernel_launch(void* const* d_in, const int* in_sizes, int n_in,
                              void* d_out, int out_size, void* d_ws, size_t ws_size,
                              hipStream_t stream) {
    const float* x     = (const float*)d_in[0];
    const float* sig   = (const float*)d_in[1];
    const int*   steps = (const int*)d_in[2];
    float* out = (float*)d_out;

    const size_t need = (size_t)WOFF + (size_t)NSIG * WDIM * WDIM * 2;
    if (ws_size >= need) {
        int* q = (int*)d_ws;
        _Float16* Wg = (_Float16*)((char*)d_ws + WOFF);
        build_all<<<257, 256, 0, stream>>>(sig, steps, Wg, q);
        blur_mfma<true><<<NBLK, 256, 0, stream>>>(x, out, sig, steps, q, Wg);
    } else {
        vblur_nt<<<NSAMP * 16, 256, 0, stream>>>(x, out, sig, steps);
        hblur_inplace<<<NSAMP * WDIM, 256, 0, stream>>>(out, sig, steps);
    }
}

// Round 24
// 76.234 us; speedup vs baseline: 1.6328x; 1.1844x over previous
//
#include <hip/hip_runtime.h>

#define WDIM  256
#define NSAMP 512
#define NSIG  32
#define NBLK  2048               // 512 samples x 4 j-quarters
#define QOFF  16                 // ints; queue table q[QOFF..]
#define WOFF  65536              // byte offset of W matrices inside d_ws

typedef float    f32x4 __attribute__((ext_vector_type(4)));
typedef _Float16 f16x4 __attribute__((ext_vector_type(4)));
typedef _Float16 f16x8 __attribute__((ext_vector_type(8)));
typedef __fp16   fp16x2 __attribute__((ext_vector_type(2)));

// Raw barrier without the __syncthreads vmcnt(0) drain.
#define LDS_BARRIER() do {                                         \
    asm volatile("s_waitcnt lgkmcnt(0)" ::: "memory");             \
    __builtin_amdgcn_s_barrier();                                  \
} while (0)

__device__ __forceinline__ int reflect(int q) {
    q = (q < 0) ? (-q - 1) : q;
    return (q >= WDIM) ? (2 * WDIM - 1 - q) : q;
}

// ---- kernel 1 (merged): blocks 0..255 build W matrices; block 256 the queue.
// W_s[i][r] = wz(r-i)+wz(-r-1-i)+wz(511-r-i); desc = samp|quarter<<9|step<<11|rad<<16.
__global__ __launch_bounds__(256) void build_all(const float* __restrict__ sigmas,
                                                 const int* __restrict__ steps,
                                                 _Float16* __restrict__ Wg,
                                                 int* __restrict__ q) {
    int t = threadIdx.x;
    if (blockIdx.x < 256) {
        __shared__ float wl[161];
        __shared__ float red;
        int s = blockIdx.x >> 3, og = blockIdx.x & 7;
        float sigma = sigmas[s];
        float radf = floorf(4.0f * sigma + 0.5f);
        if (t < 161) {
            float off = (float)(t - 80);
            float w = 0.0f;
            if (fabsf(off) <= radf) { float z = off / sigma; w = expf(-0.5f * z * z); }
            wl[t] = w;
        }
        __syncthreads();
        if (t < 64) {
            float v = wl[t] + wl[t + 64] + (t < 33 ? wl[t + 128] : 0.0f);
            #pragma unroll
            for (int o = 32; o > 0; o >>= 1) v += __shfl_down(v, o);
            if (t == 0) red = 1.0f / v;
        }
        __syncthreads();
        float rs = red;
        int i = t;
        _Float16* wrow = Wg + ((size_t)s << 16) + (i << 8);
        for (int rq = og * 4; rq < og * 4 + 4; ++rq) {
            f16x8 v;
            #pragma unroll
            for (int j = 0; j < 8; ++j) {
                int r = rq * 8 + j;
                int d1 = r - i, d2 = -r - 1 - i, d3 = 511 - r - i;
                float w = 0.0f;
                if (d1 >= -80 && d1 <= 80) w += wl[d1 + 80];
                if (d2 >= -80)             w += wl[d2 + 80];
                if (d3 <= 80)              w += wl[d3 + 80];
                v[j] = (_Float16)(w * rs);
            }
            *(f16x8*)(wrow + rq * 8) = v;
        }
    } else {
        __shared__ int hist[32];
        __shared__ int base[32];
        if (t < 32) hist[t] = 0;
        __syncthreads();
        int nb2[2], rd2[2], st2[2];
        #pragma unroll
        for (int k = 0; k < 2; ++k) {
            int samp = t + 256 * k;
            int st = steps[samp];
            float sigma = sigmas[st];
            int rad = (int)floorf(4.0f * sigma + 0.5f);
            st2[k] = st; rd2[k] = rad;
            nb2[k] = (2 * rad + 15) >> 3;
            atomicAdd(&hist[nb2[k]], 1);
        }
        __syncthreads();
        if (t == 0) {
            int acc = 0;
            for (int bin = 31; bin >= 0; --bin) { base[bin] = acc; acc += hist[bin]; }
        }
        __syncthreads();
        #pragma unroll
        for (int k = 0; k < 2; ++k) {
            int samp = t + 256 * k;
            int r = atomicAdd(&base[nb2[k]], 1);
            int x = r & 7;
            int p = r >> 3;
            #pragma unroll
            for (int jb = 0; jb < 4; ++jb)
                q[QOFF + (((p << 2) + jb) << 3) + x] =
                    samp | (jb << 9) | (st2[k] << 11) | (rd2[k] << 16);
        }
    }
}

// ---- kernel 2: fused MFMA blur (r20 structure, 32 KB LDS via XL/YT aliasing).
// Phase H: Yh[r][j] = sum_c X[r][c] W[j][c]; A=X staged LDS (coalesced f32 loads,
//          f16 swizzled), B=W direct f16x8 (L2-hot). Raw barriers, prefetch in
//          flight across them. XL (16 KB) lives in the low half of the 32 KB
//          buffer; after phase H's final barrier it is dead.
// ONE aliased region: Yh^T (32 KB, swizzled) overwrites it. Phase V barrier-free.
template <bool QUEUED>
__global__ __launch_bounds__(256, 4) void blur_mfma(const float* __restrict__ in,
                                                    float* __restrict__ out,
                                                    const float* __restrict__ sigmas,
                                                    const int* __restrict__ steps,
                                                    const int* __restrict__ q,
                                                    const _Float16* __restrict__ Wg) {
    __shared__ alignas(16) _Float16 LDSU[64 * 256];   // 32 KB total
    _Float16* XL = LDSU;                              // 16 KB during phase H
    _Float16* YT = LDSU;                              // 32 KB after phase H

    int b, j0, s, rad;
    if constexpr (QUEUED) {
        int d = q[QOFF + blockIdx.x];
        b = d & 511; j0 = ((d >> 9) & 3) << 6; s = (d >> 11) & 31; rad = (d >> 16) & 127;
    } else {
        int bid = blockIdx.x;
        int e = (bid & 7) * (NBLK / 8) + (bid >> 3);
        b = e >> 2; j0 = (e & 3) << 6;
        s = steps[b];
        rad = (int)floorf(4.0f * sigmas[s] + 0.5f);
    }
    const _Float16* Wm = Wg + ((size_t)s << 16);
    const float*    Xb = in + ((size_t)b << 16);

    int tt = threadIdx.x;
    int ln = tt & 63, wv = tt >> 6;
    int lm = ln & 15, lq = ln >> 4;
    int sr = tt >> 3;             // X stage row base (0..31)
    int sc = (tt & 7) * 4;        // X stage col

    int kh0 = max(0, j0 - rad) >> 5;
    int kh1 = min(WDIM - 1, j0 + 63 + rad) >> 5;

    f32x4 xs[8];
    auto ldstage = [&](int kt) {     // coalesced f32 loads (128B-contig per row)
        const float* xp = Xb + (size_t)sr * WDIM + (kt << 5) + sc;
        #pragma unroll
        for (int k = 0; k < 8; ++k)
            xs[k] = *(const f32x4*)(xp + (size_t)(k * 32) * WDIM);
    };
    auto wrstage = [&]() {           // convert + swizzled LDS writes
        #pragma unroll
        for (int k = 0; k < 8; ++k) {
            int rr = sr + 32 * k;
            union { f16x4 v; fp16x2 h[2]; } u;
            u.h[0] = __builtin_amdgcn_cvt_pkrtz(xs[k][0], xs[k][1]);
            u.h[1] = __builtin_amdgcn_cvt_pkrtz(xs[k][2], xs[k][3]);
            *(f16x4*)&XL[rr * 32 + ((((sc >> 3) ^ (rr & 3)) << 3) + (sc & 7))] = u.v;
        }
    };

    // ---------------- Phase H ----------------
    f32x4 acc[4][4];
    #pragma unroll
    for (int mt = 0; mt < 4; ++mt)
        #pragma unroll
        for (int nt = 0; nt < 4; ++nt) acc[mt][nt] = (f32x4)0.0f;

    ldstage(kh0);
    for (int kt = kh0; kt <= kh1; ++kt) {
        wrstage();                       // counted vmcnt wait lands here
        LDS_BARRIER();
        if (kt < kh1) ldstage(kt + 1);   // in flight across both barriers
        f16x8 bf[4];
        #pragma unroll
        for (int nt = 0; nt < 4; ++nt)   // W direct from L2 (blur_v-proven path)
            bf[nt] = *(const f16x8*)(Wm + (size_t)(j0 + nt * 16 + lm) * WDIM + (kt << 5) + lq * 8);
        #pragma unroll
        for (int mt = 0; mt < 4; ++mt) {
            int r = wv * 64 + mt * 16 + lm;
            f16x8 af = *(const f16x8*)&XL[r * 32 + ((lq ^ (r & 3)) << 3)];
            #pragma unroll
            for (int nt = 0; nt < 4; ++nt)
                acc[mt][nt] = __builtin_amdgcn_mfma_f32_16x16x32_f16(af, bf[nt], acc[mt][nt], 0, 0, 0);
        }
        LDS_BARRIER();                   // all XL reads done before next overwrite
    }
    // after the loop's final barrier XL is dead -> YT may overwrite it

    // Yh^T -> YT (swizzled): D row=(lq*4+g)->r, col=lm->j
    #pragma unroll
    for (int mt = 0; mt < 4; ++mt)
        #pragma unroll
        for (int nt = 0; nt < 4; ++nt) {
            int r4 = wv * 64 + mt * 16 + lq * 4;
            int j  = nt * 16 + lm;
            union { f16x4 v; fp16x2 h[2]; } u;
            u.h[0] = __builtin_amdgcn_cvt_pkrtz(acc[mt][nt][0], acc[mt][nt][1]);
            u.h[1] = __builtin_amdgcn_cvt_pkrtz(acc[mt][nt][2], acc[mt][nt][3]);
            *(f16x4*)&YT[j * 256 + ((((r4 >> 3) ^ (j & 7)) << 3) + (r4 & 7))] = u.v;
        }
    LDS_BARRIER();

    // ---------------- Phase V (barrier-free) ----------------
    f32x4 hac[4][4];
    #pragma unroll
    for (int mt = 0; mt < 4; ++mt)
        #pragma unroll
        for (int nt = 0; nt < 4; ++nt) hac[mt][nt] = (f32x4)0.0f;

    int ka[4], kb[4];
    #pragma unroll
    for (int mt = 0; mt < 4; ++mt) {
        int i0m = wv * 64 + mt * 16;
        ka[mt] = max(0, i0m - rad) >> 5;
        kb[mt] = min(WDIM - 1, i0m + 15 + rad) >> 5;
    }

    for (int kt = ka[0]; kt <= kb[3]; ++kt) {
        f16x8 bf[4];
        #pragma unroll
        for (int nt = 0; nt < 4; ++nt) {
            int j = nt * 16 + lm;
            bf[nt] = *(const f16x8*)&YT[j * 256 + ((((kt << 2) + lq) ^ (j & 7)) << 3)];
        }
        #pragma unroll
        for (int mt = 0; mt < 4; ++mt) {
            if (kt >= ka[mt] && kt <= kb[mt]) {
                f16x8 af = *(const f16x8*)(Wm + (size_t)(wv * 64 + mt * 16 + lm) * WDIM + (kt << 5) + lq * 8);
                #pragma unroll
                for (int nt = 0; nt < 4; ++nt)
                    hac[mt][nt] = __builtin_amdgcn_mfma_f32_16x16x32_f16(af, bf[nt], hac[mt][nt], 0, 0, 0);
            }
        }
    }

    float* ob = out + ((size_t)b << 16);
    #pragma unroll
    for (int mt = 0; mt < 4; ++mt)
        #pragma unroll
        for (int nt = 0; nt < 4; ++nt)
            #pragma unroll
            for (int g = 0; g < 4; ++g)
                ob[(size_t)(wv * 64 + mt * 16 + lq * 4 + g) * WDIM + j0 + nt * 16 + lm] = hac[mt][nt][g];
}

// ---------- fallback path (only if ws too small; needs no workspace) ----------
__device__ __forceinline__ int make_weights161(int b, const float* __restrict__ sigmas,
                                               const int* __restrict__ steps,
                                               float* wl, float* red) {
    int t = threadIdx.x;
    float sigma = sigmas[steps[b]];
    float radf = floorf(4.0f * sigma + 0.5f);
    if (t < 192) {
        float w = 0.0f;
        if (t < 161) {
            float off = (float)(t - 80);
            if (fabsf(off) <= radf) { float z = off / sigma; w = expf(-0.5f * z * z); }
        }
        wl[t] = w;
    }
    __syncthreads();
    if (t < 64) {
        float v = wl[t] + wl[t + 64] + wl[t + 128];
        #pragma unroll
        for (int o = 32; o > 0; o >>= 1) v += __shfl_down(v, o);
        if (t == 0) red[0] = 1.0f / v;
    }
    __syncthreads();
    float rs = red[0];
    if (t < 161) wl[t] *= rs;
    __syncthreads();
    return (int)radf;
}

__global__ __launch_bounds__(256) void vblur_nt(const float* __restrict__ in,
                                                float* __restrict__ out,
                                                const float* __restrict__ sigmas,
                                                const int* __restrict__ steps) {
    __shared__ float wl[192];
    __shared__ float red[1];
    int bid = blockIdx.x;
    int b = bid >> 4, i0 = (bid & 15) * 16;
    int rad = make_weights161(b, sigmas, steps, wl, red);
    int j = threadIdx.x;
    const float* inb = in + (size_t)b * WDIM * WDIM;
    float acc[16];
    #pragma unroll
    for (int ii = 0; ii < 16; ++ii) acc[ii] = 0.0f;
    for (int u = -rad; u <= rad; ++u) {
        float w = wl[80 + u];
        #pragma unroll
        for (int ii = 0; ii < 16; ++ii)
            acc[ii] = fmaf(w, inb[reflect(i0 + ii + u) * WDIM + j], acc[ii]);
    }
    #pragma unroll
    for (int ii = 0; ii < 16; ++ii)
        out[((size_t)b * WDIM + (i0 + ii)) * WDIM + j] = acc[ii];
}

__global__ __launch_bounds__(256) void hblur_inplace(float* __restrict__ buf,
                                                     const float* __restrict__ sigmas,
                                                     const int* __restrict__ steps) {
    __shared__ float wl[192];
    __shared__ float red[1];
    __shared__ float rp[WDIM + 160];
    int bid = blockIdx.x;
    int b = bid >> 8, i = bid & 255;
    float* row = buf + ((size_t)b * WDIM + i) * WDIM;
    int t = threadIdx.x;
    for (int s = t; s < WDIM + 160; s += 256) rp[s] = row[reflect(s - 80)];
    int rad = make_weights161(b, sigmas, steps, wl, red);
    float acc = 0.0f;
    for (int u = -rad; u <= rad; ++u) acc = fmaf(wl[80 + u], rp[80 + t + u], acc);
    row[t] = acc;
}
// --------------------------------------------------------------------------------

extern "C" void kernel_launch(void* const* d_in, const int* in_sizes, int n_in,
                              void* d_out, int out_size, void* d_ws, size_t ws_size,
                              hipStream_t stream) {
    const float* x     = (const float*)d_in[0];
    const float* sig   = (const float*)d_in[1];
    const int*   steps = (const int*)d_in[2];
    float* out = (float*)d_out;

    const size_t need = (size_t)WOFF + (size_t)NSIG * WDIM * WDIM * 2;
    if (ws_size >= need) {
        int* q = (int*)d_ws;
        _Float16* Wg = (_Float16*)((char*)d_ws + WOFF);
        build_all<<<257, 256, 0, stream>>>(sig, steps, Wg, q);
        blur_mfma<true><<<NBLK, 256, 0, stream>>>(x, out, sig, steps, q, Wg);
    } else {
        vblur_nt<<<NSAMP * 16, 256, 0, stream>>>(x, out, sig, steps);
        hblur_inplace<<<NSAMP * WDIM, 256, 0, stream>>>(out, sig, steps);
    }
}

// Round 26
// 73.237 us; speedup vs baseline: 1.6997x; 1.0409x over previous
//
#include <hip/hip_runtime.h>

#define WDIM  256
#define NSAMP 512
#define NSIG  32
#define NBLK  2048               // 512 samples x 4 j-quarters
#define QOFF  16                 // ints; queue table q[QOFF..]
#define WOFF  65536              // byte offset of W matrices inside d_ws

typedef float    f32x4 __attribute__((ext_vector_type(4)));
typedef _Float16 f16x4 __attribute__((ext_vector_type(4)));
typedef _Float16 f16x8 __attribute__((ext_vector_type(8)));
typedef __fp16   fp16x2 __attribute__((ext_vector_type(2)));

// Raw barrier without the __syncthreads vmcnt(0) drain: LDS visibility only,
// global prefetch loads stay in flight across it (T4 counted-vmcnt pattern).
#define LDS_BARRIER() do {                                         \
    asm volatile("s_waitcnt lgkmcnt(0)" ::: "memory");             \
    __builtin_amdgcn_s_barrier();                                  \
} while (0)

__device__ __forceinline__ int reflect(int q) {
    q = (q < 0) ? (-q - 1) : q;
    return (q >= WDIM) ? (2 * WDIM - 1 - q) : q;
}

// ---- kernel 1 (merged): blocks 0..255 build W matrices; block 256 the queue.
// W_s[i][r] = wz(r-i)+wz(-r-1-i)+wz(511-r-i); desc = samp|quarter<<9|step<<11|rad<<16.
__global__ __launch_bounds__(256) void build_all(const float* __restrict__ sigmas,
                                                 const int* __restrict__ steps,
                                                 _Float16* __restrict__ Wg,
                                                 int* __restrict__ q) {
    int t = threadIdx.x;
    if (blockIdx.x < 256) {
        __shared__ float wl[161];
        __shared__ float red;
        int s = blockIdx.x >> 3, og = blockIdx.x & 7;
        float sigma = sigmas[s];
        float radf = floorf(4.0f * sigma + 0.5f);
        if (t < 161) {
            float off = (float)(t - 80);
            float w = 0.0f;
            if (fabsf(off) <= radf) { float z = off / sigma; w = expf(-0.5f * z * z); }
            wl[t] = w;
        }
        __syncthreads();
        if (t < 64) {
            float v = wl[t] + wl[t + 64] + (t < 33 ? wl[t + 128] : 0.0f);
            #pragma unroll
            for (int o = 32; o > 0; o >>= 1) v += __shfl_down(v, o);
            if (t == 0) red = 1.0f / v;
        }
        __syncthreads();
        float rs = red;
        int i = t;
        _Float16* wrow = Wg + ((size_t)s << 16) + (i << 8);
        for (int rq = og * 4; rq < og * 4 + 4; ++rq) {
            f16x8 v;
            #pragma unroll
            for (int j = 0; j < 8; ++j) {
                int r = rq * 8 + j;
                int d1 = r - i, d2 = -r - 1 - i, d3 = 511 - r - i;
                float w = 0.0f;
                if (d1 >= -80 && d1 <= 80) w += wl[d1 + 80];
                if (d2 >= -80)             w += wl[d2 + 80];
                if (d3 <= 80)              w += wl[d3 + 80];
                v[j] = (_Float16)(w * rs);
            }
            *(f16x8*)(wrow + rq * 8) = v;
        }
    } else {
        __shared__ int hist[32];
        __shared__ int base[32];
        if (t < 32) hist[t] = 0;
        __syncthreads();
        int nb2[2], rd2[2], st2[2];
        #pragma unroll
        for (int k = 0; k < 2; ++k) {
            int samp = t + 256 * k;
            int st = steps[samp];
            float sigma = sigmas[st];
            int rad = (int)floorf(4.0f * sigma + 0.5f);
            st2[k] = st; rd2[k] = rad;
            nb2[k] = (2 * rad + 15) >> 3;
            atomicAdd(&hist[nb2[k]], 1);
        }
        __syncthreads();
        if (t == 0) {
            int acc = 0;
            for (int bin = 31; bin >= 0; --bin) { base[bin] = acc; acc += hist[bin]; }
        }
        __syncthreads();
        #pragma unroll
        for (int k = 0; k < 2; ++k) {
            int samp = t + 256 * k;
            int r = atomicAdd(&base[nb2[k]], 1);
            int x = r & 7;
            int p = r >> 3;
            #pragma unroll
            for (int jb = 0; jb < 4; ++jb)
                q[QOFF + (((p << 2) + jb) << 3) + x] =
                    samp | (jb << 9) | (st2[k] << 11) | (rd2[k] << 16);
        }
    }
}

// ---- kernel 2: fused MFMA blur, double-buffered staging, 1 barrier/tile. ----
// Phase H: Yh[r][j] = sum_c X[r][c] W[j][c]; X+W staged into alternating LDS
//   buffers; per tile: {wr(next buf) [counted vmcnt] -> reissue loads(kt+2) ->
//   compute(cur buf) -> LDS_BARRIER}. Loads never drain: in flight across
//   barrier + an entire tile of compute.
// Phase V: barrier-free; A=W direct (L2-hot), B=YT LDS (aliases dead XL dbuf).
template <bool QUEUED>
__global__ __launch_bounds__(256, 3) void blur_mfma(const float* __restrict__ in,
                                                    float* __restrict__ out,
                                                    const float* __restrict__ sigmas,
                                                    const int* __restrict__ steps,
                                                    const int* __restrict__ q,
                                                    const _Float16* __restrict__ Wg) {
    __shared__ alignas(16) _Float16 LDSU[20 * 1024];   // 40 KB
    // layout (halfs): XL buf p at p*8192 (2x16KB), WH buf p at 16384 + p*2048
    // (2x4KB), YT = LDSU (32KB, aliases XL dbuf which is dead in phase V).

    int b, j0, s, rad;
    if constexpr (QUEUED) {
        int d = q[QOFF + blockIdx.x];
        b = d & 511; j0 = ((d >> 9) & 3) << 6; s = (d >> 11) & 31; rad = (d >> 16) & 127;
    } else {
        int bid = blockIdx.x;
        int e = (bid & 7) * (NBLK / 8) + (bid >> 3);
        b = e >> 2; j0 = (e & 3) << 6;
        s = steps[b];
        rad = (int)floorf(4.0f * sigmas[s] + 0.5f);
    }
    const _Float16* Wm = Wg + ((size_t)s << 16);
    const float*    Xb = in + ((size_t)b << 16);

    int tt = threadIdx.x;
    int ln = tt & 63, wv = tt >> 6;
    int lm = ln & 15, lq = ln >> 4;
    int sr = tt >> 3;             // X stage row base (0..31)
    int sc = (tt & 7) * 4;        // X stage col
    int sj = tt >> 2;             // W stage j (0..63)
    int sw8 = (tt & 3) * 8;       // W stage c chunk

    int kh0 = max(0, j0 - rad) >> 5;
    int kh1 = min(WDIM - 1, j0 + 63 + rad) >> 5;

    f32x4 xs[8];                  // single staging register set (reissued)
    f16x8 wst;
    auto ldstage = [&](int kt) {  // coalesced loads (128B-contig row segments)
        const float* xp = Xb + (size_t)sr * WDIM + (kt << 5) + sc;
        #pragma unroll
        for (int k = 0; k < 8; ++k)
            xs[k] = *(const f32x4*)(xp + (size_t)(k * 32) * WDIM);
        wst = *(const f16x8*)(Wm + (size_t)(j0 + sj) * WDIM + (kt << 5) + sw8);
    };
    auto wrstage = [&](int p) {   // convert + swizzled LDS writes into buffer p
        _Float16* XL = LDSU + p * 8192;
        #pragma unroll
        for (int k = 0; k < 8; ++k) {
            int rr = sr + 32 * k;
            union { f16x4 v; fp16x2 h[2]; } u;
            u.h[0] = __builtin_amdgcn_cvt_pkrtz(xs[k][0], xs[k][1]);
            u.h[1] = __builtin_amdgcn_cvt_pkrtz(xs[k][2], xs[k][3]);
            *(f16x4*)&XL[rr * 32 + ((((sc >> 3) ^ (rr & 3)) << 3) + (sc & 7))] = u.v;
        }
        _Float16* WH = LDSU + 16384 + p * 2048;
        *(f16x8*)&WH[sj * 32 + (((tt & 3) ^ (sj & 3)) << 3)] = wst;
    };

    // ---------------- Phase H ----------------
    f32x4 acc[4][4];
    #pragma unroll
    for (int mt = 0; mt < 4; ++mt)
        #pragma unroll
        for (int nt = 0; nt < 4; ++nt) acc[mt][nt] = (f32x4)0.0f;

    // prologue: tile kh0 -> buf0, issue tile kh0+1
    ldstage(kh0);
    wrstage(0);
    if (kh0 + 1 <= kh1) ldstage(kh0 + 1);
    LDS_BARRIER();

    int cur = 0;
    for (int kt = kh0; kt <= kh1; ++kt) {
        if (kt < kh1) {
            wrstage(cur ^ 1);              // counted vmcnt wait (tile kt+1 loads)
            if (kt + 2 <= kh1) ldstage(kt + 2);   // reissue: in flight across barrier
        }
        _Float16* XL = LDSU + cur * 8192;
        _Float16* WH = LDSU + 16384 + cur * 2048;
        f16x8 bf[4];
        #pragma unroll
        for (int nt = 0; nt < 4; ++nt) {
            int j = nt * 16 + lm;
            bf[nt] = *(const f16x8*)&WH[j * 32 + ((lq ^ (j & 3)) << 3)];
        }
        #pragma unroll
        for (int mt = 0; mt < 4; ++mt) {
            int r = wv * 64 + mt * 16 + lm;
            f16x8 af = *(const f16x8*)&XL[r * 32 + ((lq ^ (r & 3)) << 3)];
            #pragma unroll
            for (int nt = 0; nt < 4; ++nt)
                acc[mt][nt] = __builtin_amdgcn_mfma_f32_16x16x32_f16(af, bf[nt], acc[mt][nt], 0, 0, 0);
        }
        LDS_BARRIER();   // ONE barrier per tile: publishes buf cur^1, retires reads of cur
        cur ^= 1;
    }

    // Yh^T -> YT (swizzled; XL dbuf dead after final barrier)
    _Float16* YT = LDSU;
    #pragma unroll
    for (int mt = 0; mt < 4; ++mt)
        #pragma unroll
        for (int nt = 0; nt < 4; ++nt) {
            int r4 = wv * 64 + mt * 16 + lq * 4;
            int j  = nt * 16 + lm;
            union { f16x4 v; fp16x2 h[2]; } u;
            u.h[0] = __builtin_amdgcn_cvt_pkrtz(acc[mt][nt][0], acc[mt][nt][1]);
            u.h[1] = __builtin_amdgcn_cvt_pkrtz(acc[mt][nt][2], acc[mt][nt][3]);
            *(f16x4*)&YT[j * 256 + ((((r4 >> 3) ^ (j & 7)) << 3) + (r4 & 7))] = u.v;
        }
    LDS_BARRIER();

    // ---------------- Phase V (barrier-free) ----------------
    f32x4 hac[4][4];
    #pragma unroll
    for (int mt = 0; mt < 4; ++mt)
        #pragma unroll
        for (int nt = 0; nt < 4; ++nt) hac[mt][nt] = (f32x4)0.0f;

    int ka[4], kb[4];
    #pragma unroll
    for (int mt = 0; mt < 4; ++mt) {
        int i0m = wv * 64 + mt * 16;
        ka[mt] = max(0, i0m - rad) >> 5;
        kb[mt] = min(WDIM - 1, i0m + 15 + rad) >> 5;
    }

    for (int kt = ka[0]; kt <= kb[3]; ++kt) {
        f16x8 bf[4];
        #pragma unroll
        for (int nt = 0; nt < 4; ++nt) {
            int j = nt * 16 + lm;
            bf[nt] = *(const f16x8*)&YT[j * 256 + ((((kt << 2) + lq) ^ (j & 7)) << 3)];
        }
        #pragma unroll
        for (int mt = 0; mt < 4; ++mt) {
            if (kt >= ka[mt] && kt <= kb[mt]) {
                f16x8 af = *(const f16x8*)(Wm + (size_t)(wv * 64 + mt * 16 + lm) * WDIM + (kt << 5) + lq * 8);
                #pragma unroll
                for (int nt = 0; nt < 4; ++nt)
                    hac[mt][nt] = __builtin_amdgcn_mfma_f32_16x16x32_f16(af, bf[nt], hac[mt][nt], 0, 0, 0);
            }
        }
    }

    float* ob = out + ((size_t)b << 16);
    #pragma unroll
    for (int mt = 0; mt < 4; ++mt)
        #pragma unroll
        for (int nt = 0; nt < 4; ++nt)
            #pragma unroll
            for (int g = 0; g < 4; ++g)
                ob[(size_t)(wv * 64 + mt * 16 + lq * 4 + g) * WDIM + j0 + nt * 16 + lm] = hac[mt][nt][g];
}

// ---------- fallback path (only if ws too small; needs no workspace) ----------
__device__ __forceinline__ int make_weights161(int b, const float* __restrict__ sigmas,
                                               const int* __restrict__ steps,
                                               float* wl, float* red) {
    int t = threadIdx.x;
    float sigma = sigmas[steps[b]];
    float radf = floorf(4.0f * sigma + 0.5f);
    if (t < 192) {
        float w = 0.0f;
        if (t < 161) {
            float off = (float)(t - 80);
            if (fabsf(off) <= radf) { float z = off / sigma; w = expf(-0.5f * z * z); }
        }
        wl[t] = w;
    }
    __syncthreads();
    if (t < 64) {
        float v = wl[t] + wl[t + 64] + wl[t + 128];
        #pragma unroll
        for (int o = 32; o > 0; o >>= 1) v += __shfl_down(v, o);
        if (t == 0) red[0] = 1.0f / v;
    }
    __syncthreads();
    float rs = red[0];
    if (t < 161) wl[t] *= rs;
    __syncthreads();
    return (int)radf;
}

__global__ __launch_bounds__(256) void vblur_nt(const float* __restrict__ in,
                                                float* __restrict__ out,
                                                const float* __restrict__ sigmas,
                                                const int* __restrict__ steps) {
    __shared__ float wl[192];
    __shared__ float red[1];
    int bid = blockIdx.x;
    int b = bid >> 4, i0 = (bid & 15) * 16;
    int rad = make_weights161(b, sigmas, steps, wl, red);
    int j = threadIdx.x;
    const float* inb = in + (size_t)b * WDIM * WDIM;
    float acc[16];
    #pragma unroll
    for (int ii = 0; ii < 16; ++ii) acc[ii] = 0.0f;
    for (int u = -rad; u <= rad; ++u) {
        float w = wl[80 + u];
        #pragma unroll
        for (int ii = 0; ii < 16; ++ii)
            acc[ii] = fmaf(w, inb[reflect(i0 + ii + u) * WDIM + j], acc[ii]);
    }
    #pragma unroll
    for (int ii = 0; ii < 16; ++ii)
        out[((size_t)b * WDIM + (i0 + ii)) * WDIM + j] = acc[ii];
}

__global__ __launch_bounds__(256) void hblur_inplace(float* __restrict__ buf,
                                                     const float* __restrict__ sigmas,
                                                     const int* __restrict__ steps) {
    __shared__ float wl[192];
    __shared__ float red[1];
    __shared__ float rp[WDIM + 160];
    int bid = blockIdx.x;
    int b = bid >> 8, i = bid & 255;
    float* row = buf + ((size_t)b * WDIM + i) * WDIM;
    int t = threadIdx.x;
    for (int s = t; s < WDIM + 160; s += 256) rp[s] = row[reflect(s - 80)];
    int rad = make_weights161(b, sigmas, steps, wl, red);
    float acc = 0.0f;
    for (int u = -rad; u <= rad; ++u) acc = fmaf(wl[80 + u], rp[80 + t + u], acc);
    row[t] = acc;
}
// --------------------------------------------------------------------------------

extern "C" void kernel_launch(void* const* d_in, const int* in_sizes, int n_in,
                              void* d_out, int out_size, void* d_ws, size_t ws_size,
                              hipStream_t stream) {
    const float* x     = (const float*)d_in[0];
    const float* sig   = (const float*)d_in[1];
    const int*   steps = (const int*)d_in[2];
    float* out = (float*)d_out;

    const size_t need = (size_t)WOFF + (size_t)NSIG * WDIM * WDIM * 2;
    if (ws_size >= need) {
        int* q = (int*)d_ws;
        _Float16* Wg = (_Float16*)((char*)d_ws + WOFF);
        build_all<<<257, 256, 0, stream>>>(sig, steps, Wg, q);
        blur_mfma<true><<<NBLK, 256, 0, stream>>>(x, out, sig, steps, q, Wg);
    } else {
        vblur_nt<<<NSAMP * 16, 256, 0, stream>>>(x, out, sig, steps);
        hblur_inplace<<<NSAMP * WDIM, 256, 0, stream>>>(out, sig, steps);
    }
}